// Round 8
// baseline (80.162 us; speedup 1.0000x reference)
//
#include <hip/hip_runtime.h>

#define NQ 14
#define NSTATE (1 << NQ)
#define NT 256
#define AMPS 64

typedef float  f2  __attribute__((ext_vector_type(2)));
typedef __fp16 h2v __attribute__((ext_vector_type(2)));

// LDS: state h2 (1 dword each). Gate layout slots [0,16384), swizzle j^((j>>9)&31);
// E layout slots f + (f>>6) in [0,16640) — aliased in time (barrier-separated).
#define N_H2 16640
#define OFF_BTAB  (N_H2*4)
#define OFF_RX3   (OFF_BTAB + 28*8)
#define OFF_XX2   (OFF_RX3 + 28*4)
#define OFF_RED   (OFF_XX2 + 14*4)
#define SMEM_BYTES (OFF_RED + 4*NQ*4)

__device__ __forceinline__ f2 cmul(f2 a, f2 b){
    f2 br = {-b.y, b.x};
    return a.x * b + a.y * br;
}

// t = (ss.lo * y.hi, -ss.hi * y.lo)  -- the (y,-x) swizzle folded into VOP3P
__device__ __forceinline__ f2 pkswz(f2 ss, f2 y){
    f2 t;
    asm("v_pk_mul_f32 %0, %1, %2 op_sel:[0,1] op_sel_hi:[1,0] neg_hi:[0,1]"
        : "=v"(t) : "v"(ss), "v"(y));
    return t;
}
__device__ __forceinline__ f2 pkfma(f2 a, f2 b, f2 c){
    f2 d;
    asm("v_pk_fma_f32 %0, %1, %2, %3" : "=v"(d) : "v"(a), "v"(b), "v"(c));
    return d;
}
// A' = c*A + s*(B.y,-B.x);  B' = c*B + s*(A.y,-A.x)   (4 VOP3P total)
__device__ __forceinline__ void rot2(f2& A, f2& B, f2 cc, f2 ss){
    f2 tA = pkswz(ss, B);
    f2 tB = pkswz(ss, A);
    A = pkfma(cc, A, tA);
    B = pkfma(cc, B, tB);
}

__device__ __forceinline__ h2v pack(f2 v){ return __builtin_amdgcn_cvt_pkrtz(v.x, v.y); }
__device__ __forceinline__ f2  unpack(h2v h){ return (f2){(float)h.x, (float)h.y}; }

// quad_perm DPP shuffle of an f2 (both components), compile-time control
template<int CTRL>
__device__ __forceinline__ f2 qperm(f2 v){
    int x = __builtin_amdgcn_mov_dpp(__float_as_int(v.x), CTRL, 0xf, 0xf, true);
    int y = __builtin_amdgcn_mov_dpp(__float_as_int(v.y), CTRL, 0xf, 0xf, true);
    return (f2){__int_as_float(x), __int_as_float(y)};
}

template<int P, int M>
__device__ __forceinline__ void applyXX(f2* amp, f2 cc, f2 ss){
    #pragma unroll
    for (int L = 0; L < AMPS; ++L)
        if (!((L >> P) & 1)) rot2(amp[L], amp[L ^ M], cc, ss);
}
template<int R>
__device__ __forceinline__ void applyRX(f2* amp, f2 cc, f2 ss){
    #pragma unroll
    for (int L = 0; L < AMPS; ++L)
        if (!((L >> R) & 1)) rot2(amp[L], amp[L | (1 << R)], cc, ss);
}

// ---- pre-kernel: f = pi^-1(j) (ascending chain; direction verified R6/R7).
// P2 mapping (NEW): j bit0 = lane l0; bits1..6 = L0..L5; bit7 = w1; bit8 = w0;
// bits 9..13 = l5,l4,l3,l2,l1.  Stored transposed: tbl[(L>>3)*2048 + t*8 + (L&7)].
__global__ void perm_tbl_kernel(unsigned short* __restrict__ tbl)
{
    const int j = blockIdx.x * blockDim.x + threadIdx.x;   // 0..16383
    int x = j;
    #pragma unroll
    for (int w = 0; w < NQ; ++w) {
        const int p1 = 13 - w;
        const int p2 = 13 - ((w + 1) % NQ);
        const int pt = 13 - ((w + 2) % NQ);
        const int cond = ((x >> p1) & ~(x >> p2)) & 1;
        x ^= cond << pt;
    }
    const int L  = (j >> 1) & 63;
    const int l  = (j & 1) | (((j >> 13) & 1) << 1) | (((j >> 12) & 1) << 2)
                 | (((j >> 11) & 1) << 3) | (((j >> 10) & 1) << 4) | (((j >> 9) & 1) << 5);
    const int w_ = (((j >> 7) & 1) << 1) | ((j >> 8) & 1);
    const int t  = (w_ << 6) | l;
    tbl[(L >> 3) * 2048 + t * 8 + (L & 7)] = (unsigned short)x;
}

__global__ void __launch_bounds__(NT, 2)
qsim_kernel(const float* __restrict__ cp, const float* __restrict__ p,
            const unsigned short* __restrict__ tblD, float* __restrict__ out)
{
    extern __shared__ __align__(16) char smem[];
    h2v* st    = reinterpret_cast<h2v*>(smem);
    f2*  Btab  = reinterpret_cast<f2*>(smem + OFF_BTAB);
    float* rx3c = reinterpret_cast<float*>(smem + OFF_RX3);
    float* rx3s = rx3c + 14;
    float* xx2c = reinterpret_cast<float*>(smem + OFF_XX2);
    float* xx2s = xx2c + 7;
    float* red  = reinterpret_cast<float*>(smem + OFF_RED);

    const int b = blockIdx.x;
    const int t = threadIdx.x;
    const float* pb  = p  + b * 42;   // p[b][3][14]
    const float* cpb = cp + b * 14;   // cp[b][14]

    // ---- per-block tables (RX1 x XX1 x RZ fused into 7 two-qubit blocks) ----
    if (t < 7) {
        const int ws = t, wa = 2*ws, wb = 2*ws + 1;
        float sa, ca; sincosf(0.5f * pb[wa], &sa, &ca);
        float sb, cb; sincosf(0.5f * pb[wb], &sb, &cb);
        f2 s00 = {ca*cb, 0.f};
        f2 s01 = {0.f, -ca*sb};
        f2 s10 = {0.f, -sa*cb};
        f2 s11 = {-sa*sb, 0.f};
        float sx, cx; sincosf(0.5f * cpb[ws], &sx, &cx);
        rot2(s00, s11, (f2){cx,cx}, (f2){sx,sx});
        rot2(s01, s10, (f2){cx,cx}, (f2){sx,sx});
        const float ga = 0.5f * pb[14 + wa], gb = 0.5f * pb[14 + wb];
        float sA, cA; sincosf(ga + gb, &sA, &cA);
        float sB, cB; sincosf(gb - ga, &sB, &cB);
        s00 = cmul(s00, (f2){cA, -sA});
        s11 = cmul(s11, (f2){cA,  sA});
        s01 = cmul(s01, (f2){cB,  sB});
        s10 = cmul(s10, (f2){cB, -sB});
        const int k = 6 - ws;                 // crumb k = state bits (2k+1,2k)
        Btab[k*4+0] = s00; Btab[k*4+1] = s01; Btab[k*4+2] = s10; Btab[k*4+3] = s11;
    } else if (t >= 64 && t < 78) {
        const int w = t - 64;
        float s, c; sincosf(0.5f * pb[28 + w], &s, &c);
        rx3c[w] = c; rx3s[w] = s;
    } else if (t >= 128 && t < 135) {
        const int g = t - 128;
        float s, c; sincosf(0.5f * cpb[7 + g], &s, &c);
        xx2c[g] = c; xx2s[g] = s;
    }
    __syncthreads();

    f2 amp[AMPS];
    f2 cc, ss;
    #define LOADXX(g) do { float c_ = xx2c[g], s_ = xx2s[g]; cc = (f2){c_,c_}; ss = (f2){s_,s_}; } while (0)
    #define LOADRX(w) do { float c_ = rx3c[w], s_ = rx3s[w]; cc = (f2){c_,c_}; ss = (f2){s_,s_}; } while (0)

    // ==== P1: build + XX(1,2),(3,4),(5,6) + RX(1..6).  Local bits {12..7} (L0->bit7).
    // Thread: t[6:0]->bits{6..0}, t7->bit13.
    {
        const int t6 = (t >> 6) & 1, t7 = t >> 7;
        f2 Pc = cmul(cmul(Btab[t & 3], Btab[4 + ((t >> 2) & 3)]), Btab[8 + ((t >> 4) & 3)]);
        f2 P3a0 = cmul(Pc, Btab[12 + t6]);        // L0=0  (c3 idx = L0<<1|t6)
        f2 P3a1 = cmul(Pc, Btab[12 + 2 + t6]);    // L0=1
        f2 G00 = cmul(P3a0, Btab[24 + (t7 << 1)]);      // L5=0 (c6 idx = t7<<1|L5)
        f2 G01 = cmul(P3a0, Btab[24 + (t7 << 1) + 1]);  // L5=1
        f2 G10 = cmul(P3a1, Btab[24 + (t7 << 1)]);
        f2 G11 = cmul(P3a1, Btab[24 + (t7 << 1) + 1]);
        #pragma unroll
        for (int m = 0; m < 16; ++m) {            // m = L[4:1]; c4 = m&3, c5 = m>>2
            f2 H = cmul(Btab[16 + (m & 3)], Btab[20 + (m >> 2)]);
            amp[(m << 1)]          = cmul(G00, H);
            amp[(m << 1) | 1]      = cmul(G10, H);
            amp[32 | (m << 1)]     = cmul(G01, H);
            amp[32 | (m << 1) | 1] = cmul(G11, H);
        }
        LOADXX(0); applyXX<5, 0x30>(amp, cc, ss);   // XX(1,2) on (L5,L4)
        LOADXX(1); applyXX<3, 0x0C>(amp, cc, ss);   // XX(3,4) on (L3,L2)
        LOADXX(2); applyXX<1, 0x03>(amp, cc, ss);   // XX(5,6) on (L1,L0)
        LOADRX(1); applyRX<5>(amp, cc, ss);
        LOADRX(2); applyRX<4>(amp, cc, ss);
        LOADRX(3); applyRX<3>(amp, cc, ss);
        LOADRX(4); applyRX<2>(amp, cc, ss);
        LOADRX(5); applyRX<1>(amp, cc, ss);
        LOADRX(6); applyRX<0>(amp, cc, ss);
        const int jhi = (t7 << 13) | (t & 127);
        #pragma unroll
        for (int L = 0; L < AMPS; ++L) {
            const int j = jhi | (L << 7);
            st[j ^ ((j >> 9) & 31)] = pack(amp[L]);
        }
    }
    __syncthreads();

    // ==== P2: XX(7,8),(9,10),(11,12) + RX(7..12) on local bits {6..1} (L0->bit1),
    // then P3 = XX(13,0)+RX(13)+RX(0) IN REGISTERS via quad DPP (bits 0,13 = lanes l0,l1),
    // then scatter through pi^-1 to E layout.
    {
        uint4 tv[8];
        const uint4* tq = reinterpret_cast<const uint4*>(tblD);
        #pragma unroll
        for (int g = 0; g < 8; ++g) tv[g] = tq[g * 256 + t];   // issued early

        const int l = t & 63, w_ = t >> 6;
        const int jbase = (l & 1) | (((w_ >> 1) & 1) << 7) | ((w_ & 1) << 8)
                        | (((l >> 5) & 1) << 9) | (((l >> 4) & 1) << 10)
                        | (((l >> 3) & 1) << 11) | (((l >> 2) & 1) << 12)
                        | (((l >> 1) & 1) << 13);
        const int jb2 = jbase ^ ((jbase >> 9) & 31);
        #pragma unroll
        for (int L = 0; L < AMPS; ++L)
            amp[L] = unpack(st[jb2 ^ (L << 1)]);
        LOADXX(3); applyXX<5, 0x30>(amp, cc, ss);   // XX(7,8)  on bits(6,5)=(L5,L4)
        LOADXX(4); applyXX<3, 0x0C>(amp, cc, ss);   // XX(9,10) on bits(4,3)=(L3,L2)
        LOADXX(5); applyXX<1, 0x03>(amp, cc, ss);   // XX(11,12) on bits(2,1)=(L1,L0)
        LOADRX(7);  applyRX<5>(amp, cc, ss);
        LOADRX(8);  applyRX<4>(amp, cc, ss);
        LOADRX(9);  applyRX<3>(amp, cc, ss);
        LOADRX(10); applyRX<2>(amp, cc, ss);
        LOADRX(11); applyRX<1>(amp, cc, ss);
        LOADRX(12); applyRX<0>(amp, cc, ss);
        // P3: bit0=l0, bit13=l1. XX(13,0): partner l^3; RX(13)->bit0: l^1; RX(0)->bit13: l^2.
        // Cross-lane rot is symmetric: X' = c*X + s*(P.y, -P.x).
        LOADXX(6);
        #pragma unroll
        for (int L = 0; L < AMPS; ++L) { f2 pv = qperm<0x1B>(amp[L]); amp[L] = pkfma(cc, amp[L], pkswz(ss, pv)); }
        LOADRX(13);
        #pragma unroll
        for (int L = 0; L < AMPS; ++L) { f2 pv = qperm<0xB1>(amp[L]); amp[L] = pkfma(cc, amp[L], pkswz(ss, pv)); }
        LOADRX(0);
        #pragma unroll
        for (int L = 0; L < AMPS; ++L) { f2 pv = qperm<0x4E>(amp[L]); amp[L] = pkfma(cc, amp[L], pkswz(ss, pv)); }
        __syncthreads();   // all gate-layout reads complete; E layout may overwrite
        #pragma unroll
        for (int L = 0; L < AMPS; ++L) {
            const unsigned comp = (L & 4) ? ((L & 2) ? tv[L >> 3].w : tv[L >> 3].z)
                                          : ((L & 2) ? tv[L >> 3].y : tv[L >> 3].x);
            const unsigned f = (L & 1) ? (comp >> 16) : (comp & 0xffffu);
            st[f + (f >> 6)] = pack(amp[L]);       // eslot = (f>>6)*65 + (f&63)
        }
    }
    __syncthreads();

    // ==== E: contiguous conflict-free reads; final index f = t*64 + k.
    //   k bits 0..5 -> wires 13..8 (in-register tree, U0..U5)
    //   lane bits 0..5 -> wires 7..2 (sign-tracking butterfly d0..d5)
    //   wave bits 0..1 -> wires 1..0 (wave-uniform +-s)
    {
        const h2v* erow = st + t * 65;
        float U0, U1 = 0.f, U2 = 0.f, U4, U5, T;
        float C[8];
        float u0acc = 0.f;
        #pragma unroll
        for (int ch = 0; ch < 8; ++ch) {
            float q[8];
            #pragma unroll
            for (int e = 0; e < 8; ++e) {
                const f2 a = unpack(erow[ch * 8 + e]);
                q[e] = fmaf(a.x, a.x, a.y * a.y);
            }
            const float p0 = q[0] + q[1], p1 = q[2] + q[3], p2 = q[4] + q[5], p3 = q[6] + q[7];
            u0acc += (q[1] + q[3]) + (q[5] + q[7]);
            U1 += p1 + p3;
            const float s01 = p0 + p1, s23 = p2 + p3;
            U2 += s23;
            C[ch] = s01 + s23;
        }
        U0 = u0acc;
        {
            const float P0 = C[0] + C[1], P1 = C[2] + C[3], P2 = C[4] + C[5], P3v = C[6] + C[7];
            const float U3v = (C[1] + C[3]) + (C[5] + C[7]);
            U4 = P1 + P3v;
            const float Q0 = P0 + P1, Q1 = P2 + P3v;
            U5 = Q1;
            T = Q0 + Q1;
            C[0] = U3v;
        }
        const float U3 = C[0];

        // sign-tracking butterfly over 6 lane bits (results valid at lane 0)
        float s = T;
        float d0, d1, d2, d3, d4, d5;
        {
            float o;
            o = __shfl_xor(s, 1);  d0 = s - o; s += o;
            o = __shfl_xor(d0, 2); d0 += o;
            o = __shfl_xor(s, 2);  d1 = s - o; s += o;
            o = __shfl_xor(d0, 4); d0 += o;
            o = __shfl_xor(d1, 4); d1 += o;
            o = __shfl_xor(s, 4);  d2 = s - o; s += o;
            o = __shfl_xor(d0, 8); d0 += o;
            o = __shfl_xor(d1, 8); d1 += o;
            o = __shfl_xor(d2, 8); d2 += o;
            o = __shfl_xor(s, 8);  d3 = s - o; s += o;
            o = __shfl_xor(d0, 16); d0 += o;
            o = __shfl_xor(d1, 16); d1 += o;
            o = __shfl_xor(d2, 16); d2 += o;
            o = __shfl_xor(d3, 16); d3 += o;
            o = __shfl_xor(s, 16);  d4 = s - o; s += o;
            o = __shfl_xor(d0, 32); d0 += o;
            o = __shfl_xor(d1, 32); d1 += o;
            o = __shfl_xor(d2, 32); d2 += o;
            o = __shfl_xor(d3, 32); d3 += o;
            o = __shfl_xor(d4, 32); d4 += o;
            o = __shfl_xor(s, 32);  d5 = s - o; s += o;
        }
        float V0 = U0, V1 = U1, V2 = U2, V3 = U3, V4 = U4, V5 = U5;
        #pragma unroll
        for (int m = 1; m < 64; m <<= 1) {
            V0 += __shfl_xor(V0, m);
            V1 += __shfl_xor(V1, m);
            V2 += __shfl_xor(V2, m);
            V3 += __shfl_xor(V3, m);
            V4 += __shfl_xor(V4, m);
            V5 += __shfl_xor(V5, m);
        }
        if ((t & 63) == 0) {
            const int wv = t >> 6;           // wave bits = f bits 12,13
            float* r = red + wv * NQ;
            r[0]  = (wv & 2) ? -s : s;       // f bit13 -> wire 0
            r[1]  = (wv & 1) ? -s : s;       // f bit12 -> wire 1
            r[2]  = d5;                      // f bit11 -> wire 2
            r[3]  = d4;
            r[4]  = d3;
            r[5]  = d2;
            r[6]  = d1;
            r[7]  = d0;                      // f bit6 -> wire 7
            r[8]  = s - 2.f * V5;            // f bit5 -> wire 8
            r[9]  = s - 2.f * V4;
            r[10] = s - 2.f * V3;
            r[11] = s - 2.f * V2;
            r[12] = s - 2.f * V1;
            r[13] = s - 2.f * V0;            // f bit0 -> wire 13
        }
    }
    __syncthreads();
    if (t < NQ) {
        out[b * NQ + t] = (red[t] + red[NQ + t]) + (red[2 * NQ + t] + red[3 * NQ + t]);
    }
    #undef LOADXX
    #undef LOADRX
}

extern "C" void kernel_launch(void* const* d_in, const int* in_sizes, int n_in,
                              void* d_out, int out_size, void* d_ws, size_t ws_size,
                              hipStream_t stream)
{
    (void)n_in; (void)out_size; (void)ws_size;
    const float* cp = (const float*)d_in[0];
    const float* p  = (const float*)d_in[1];
    float* out = (float*)d_out;
    unsigned short* tbl = (unsigned short*)d_ws;        // 32 KiB
    const int B = in_sizes[0] / NQ;   // 512

    perm_tbl_kernel<<<NSTATE / 256, 256, 0, stream>>>(tbl);

    (void)hipFuncSetAttribute(reinterpret_cast<const void*>(qsim_kernel),
                              hipFuncAttributeMaxDynamicSharedMemorySize, SMEM_BYTES);
    qsim_kernel<<<B, NT, SMEM_BYTES, stream>>>(cp, p, tbl, out);
}

// Round 9
// 79.146 us; speedup vs baseline: 1.0128x; 1.0128x over previous
//
#include <hip/hip_runtime.h>

#define NQ 14
#define NSTATE (1 << NQ)
#define NT 512
#define AMPS 32

typedef float  f2  __attribute__((ext_vector_type(2)));
typedef __fp16 h2v __attribute__((ext_vector_type(2)));

// LDS: state h2 (1 dword each). Gate layout slots [0,16384), swizzle j^((j>>5)&31);
// E layout slots f + (f>>6) in [0,16640) — aliased in time (barrier-separated).
#define N_H2 16640
#define OFF_BTAB  (N_H2*4)
#define OFF_RX3   (OFF_BTAB + 28*8)
#define OFF_XX2   (OFF_RX3 + 28*4)
#define OFF_RED   (OFF_XX2 + 14*4)
#define SMEM_BYTES (OFF_RED + 8*NQ*4)

__device__ __forceinline__ f2 cmul(f2 a, f2 b){
    f2 br = {-b.y, b.x};
    return a.x * b + a.y * br;
}

// t = (ss.lo * y.hi, -ss.hi * y.lo)  -- the (y,-x) swizzle folded into VOP3P
__device__ __forceinline__ f2 pkswz(f2 ss, f2 y){
    f2 t;
    asm("v_pk_mul_f32 %0, %1, %2 op_sel:[0,1] op_sel_hi:[1,0] neg_hi:[0,1]"
        : "=v"(t) : "v"(ss), "v"(y));
    return t;
}
__device__ __forceinline__ f2 pkfma(f2 a, f2 b, f2 c){
    f2 d;
    asm("v_pk_fma_f32 %0, %1, %2, %3" : "=v"(d) : "v"(a), "v"(b), "v"(c));
    return d;
}
// A' = c*A + s*(B.y,-B.x);  B' = c*B + s*(A.y,-A.x)   (4 VOP3P total)
__device__ __forceinline__ void rot2(f2& A, f2& B, f2 cc, f2 ss){
    f2 tA = pkswz(ss, B);
    f2 tB = pkswz(ss, A);
    A = pkfma(cc, A, tA);
    B = pkfma(cc, B, tB);
}

__device__ __forceinline__ h2v pack(f2 v){ return __builtin_amdgcn_cvt_pkrtz(v.x, v.y); }
__device__ __forceinline__ f2  unpack(h2v h){ return (f2){(float)h.x, (float)h.y}; }

// quad_perm DPP shuffle of an f2 (both components), compile-time control
template<int CTRL>
__device__ __forceinline__ f2 qperm(f2 v){
    int x = __builtin_amdgcn_mov_dpp(__float_as_int(v.x), CTRL, 0xf, 0xf, true);
    int y = __builtin_amdgcn_mov_dpp(__float_as_int(v.y), CTRL, 0xf, 0xf, true);
    return (f2){__int_as_float(x), __int_as_float(y)};
}

template<int P, int M>
__device__ __forceinline__ void applyXX(f2* amp, f2 cc, f2 ss){
    #pragma unroll
    for (int L = 0; L < AMPS; ++L)
        if (!((L >> P) & 1)) rot2(amp[L], amp[L ^ M], cc, ss);
}
template<int R>
__device__ __forceinline__ void applyRX(f2* amp, f2 cc, f2 ss){
    #pragma unroll
    for (int L = 0; L < AMPS; ++L)
        if (!((L >> R) & 1)) rot2(amp[L], amp[L | (1 << R)], cc, ss);
}

// ---- pre-kernel: f = pi^-1(j) (ascending chain; direction verified R6-R8).
// P3 mapping: j13 = t0; j[12:5] = t[8:1]; j[4:0] = L.
// Stored thread-contiguous: tbl[t*32 + L] = f  (64B per thread, coalesced).
__global__ void perm_tbl_kernel(unsigned short* __restrict__ tbl)
{
    const int j = blockIdx.x * blockDim.x + threadIdx.x;   // 0..16383
    int x = j;
    #pragma unroll
    for (int w = 0; w < NQ; ++w) {
        const int p1 = 13 - w;
        const int p2 = 13 - ((w + 1) % NQ);
        const int pt = 13 - ((w + 2) % NQ);
        const int cond = ((x >> p1) & ~(x >> p2)) & 1;
        x ^= cond << pt;
    }
    const int L = j & 31;
    const int t = (j >> 13) | (((j >> 5) & 0xFF) << 1);
    tbl[t * 32 + L] = (unsigned short)x;
}

__global__ void __launch_bounds__(NT, 4)
qsim_kernel(const float* __restrict__ cp, const float* __restrict__ p,
            const unsigned short* __restrict__ tblD, float* __restrict__ out)
{
    extern __shared__ __align__(16) char smem[];
    h2v* st    = reinterpret_cast<h2v*>(smem);
    f2*  Btab  = reinterpret_cast<f2*>(smem + OFF_BTAB);
    float* rx3c = reinterpret_cast<float*>(smem + OFF_RX3);
    float* rx3s = rx3c + 14;
    float* xx2c = reinterpret_cast<float*>(smem + OFF_XX2);
    float* xx2s = xx2c + 7;
    float* red  = reinterpret_cast<float*>(smem + OFF_RED);

    const int b = blockIdx.x;
    const int t = threadIdx.x;
    const float* pb  = p  + b * 42;   // p[b][3][14]
    const float* cpb = cp + b * 14;   // cp[b][14]

    // ---- per-block tables (RX1 x XX1 x RZ fused into 7 two-qubit blocks) ----
    if (t < 7) {
        const int ws = t, wa = 2*ws, wb = 2*ws + 1;
        float sa, ca; sincosf(0.5f * pb[wa], &sa, &ca);
        float sb, cb; sincosf(0.5f * pb[wb], &sb, &cb);
        f2 s00 = {ca*cb, 0.f};
        f2 s01 = {0.f, -ca*sb};
        f2 s10 = {0.f, -sa*cb};
        f2 s11 = {-sa*sb, 0.f};
        float sx, cx; sincosf(0.5f * cpb[ws], &sx, &cx);
        rot2(s00, s11, (f2){cx,cx}, (f2){sx,sx});
        rot2(s01, s10, (f2){cx,cx}, (f2){sx,sx});
        const float ga = 0.5f * pb[14 + wa], gb = 0.5f * pb[14 + wb];
        float sA, cA; sincosf(ga + gb, &sA, &cA);
        float sB, cB; sincosf(gb - ga, &sB, &cB);
        s00 = cmul(s00, (f2){cA, -sA});
        s11 = cmul(s11, (f2){cA,  sA});
        s01 = cmul(s01, (f2){cB,  sB});
        s10 = cmul(s10, (f2){cB, -sB});
        const int k = 6 - ws;                 // crumb k = state bits (2k+1,2k)
        Btab[k*4+0] = s00; Btab[k*4+1] = s01; Btab[k*4+2] = s10; Btab[k*4+3] = s11;
    } else if (t >= 64 && t < 78) {
        const int w = t - 64;
        float s, c; sincosf(0.5f * pb[28 + w], &s, &c);
        rx3c[w] = c; rx3s[w] = s;
    } else if (t >= 128 && t < 135) {
        const int g = t - 128;
        float s, c; sincosf(0.5f * cpb[7 + g], &s, &c);
        xx2c[g] = c; xx2s[g] = s;
    }
    __syncthreads();

    f2 amp[AMPS];
    f2 cc, ss;
    #define LOADXX(g) do { float c_ = xx2c[g], s_ = xx2s[g]; cc = (f2){c_,c_}; ss = (f2){s_,s_}; } while (0)
    #define LOADRX(w) do { float c_ = rx3c[w], s_ = rx3s[w]; cc = (f2){c_,c_}; ss = (f2){s_,s_}; } while (0)

    // ==== P1: build + XX(1,2),(3,4) + RX(1..5).  Local L -> j[12:8] (wires 5..1).
    // Thread: t[7:0] -> j[7:0], t8 -> j13.
    {
        const int t8 = t >> 8;
        f2 Pc = cmul(cmul(Btab[t & 3], Btab[4 + ((t >> 2) & 3)]),
                     cmul(Btab[8 + ((t >> 4) & 3)], Btab[12 + ((t >> 6) & 3)]));
        f2 G0 = cmul(Pc, Btab[24 + (t8 << 1)]);       // c6 = (j13<<1)|j12, L4 = j12 = 0
        f2 G1 = cmul(Pc, Btab[24 + (t8 << 1) + 1]);   // L4 = 1
        f2 H[16];
        #pragma unroll
        for (int m = 0; m < 16; ++m)                  // m = L[3:0]: c4 = m&3 (j9:8), c5 = m>>2 (j11:10)
            H[m] = cmul(Btab[16 + (m & 3)], Btab[20 + (m >> 2)]);
        #pragma unroll
        for (int L = 0; L < AMPS; ++L)
            amp[L] = cmul((L & 16) ? G1 : G0, H[L & 15]);
        LOADXX(0); applyXX<4, 0x18>(amp, cc, ss);     // XX(1,2) on bits(12,11)=(L4,L3)
        LOADXX(1); applyXX<2, 0x06>(amp, cc, ss);     // XX(3,4) on bits(10,9)=(L2,L1)
        LOADRX(1); applyRX<4>(amp, cc, ss);           // bit12
        LOADRX(2); applyRX<3>(amp, cc, ss);
        LOADRX(3); applyRX<2>(amp, cc, ss);
        LOADRX(4); applyRX<1>(amp, cc, ss);
        LOADRX(5); applyRX<0>(amp, cc, ss);           // bit8
        const int jhi = ((t >> 8) << 13) | (t & 255);
        #pragma unroll
        for (int L = 0; L < AMPS; ++L) {
            const int j = jhi | (L << 8);
            st[j ^ ((j >> 5) & 31)] = pack(amp[L]);
        }
    }
    __syncthreads();

    // ==== P2: XX(5,6),(7,8) + RX(6..9).  Local L -> j[8:4] (wires 5..9).
    // Thread: t[3:0] -> j[3:0], t[7:4] -> j[12:9], t8 -> j13.
    {
        const int jb = (t & 15) | (((t >> 4) & 15) << 9) | ((t >> 8) << 13);
        #pragma unroll
        for (int L = 0; L < AMPS; ++L) {
            const int j = jb | (L << 4);
            amp[L] = unpack(st[j ^ ((j >> 5) & 31)]);
        }
        LOADXX(2); applyXX<4, 0x18>(amp, cc, ss);     // XX(5,6) on bits(8,7)=(L4,L3)
        LOADXX(3); applyXX<2, 0x06>(amp, cc, ss);     // XX(7,8) on bits(6,5)=(L2,L1)
        LOADRX(6); applyRX<3>(amp, cc, ss);           // bit7
        LOADRX(7); applyRX<2>(amp, cc, ss);
        LOADRX(8); applyRX<1>(amp, cc, ss);
        LOADRX(9); applyRX<0>(amp, cc, ss);           // bit4
        // write back own slots (each j owned by exactly one (t,L): no barrier needed)
        #pragma unroll
        for (int L = 0; L < AMPS; ++L) {
            const int j = jb | (L << 4);
            st[j ^ ((j >> 5) & 31)] = pack(amp[L]);
        }
    }
    __syncthreads();

    // ==== P3: XX(9,10),(11,12) + RX(10..13) local; XX(13,0)+RX(0) via quad-DPP
    // (bit13 = lane l0), then scatter through pi^-1 to E layout.
    // Local L -> j[4:0]; thread: t0 -> j13, t[8:1] -> j[12:5].
    {
        uint4 tv[4];
        {
            const uint4* tq = reinterpret_cast<const uint4*>(tblD) + t * 4;
            #pragma unroll
            for (int g = 0; g < 4; ++g) tv[g] = tq[g];     // issued early
        }
        const int jb3 = ((t & 1) << 13) | ((t >> 1) << 5); // low 5 bits zero
        const int xr  = (jb3 >> 5) & 31;
        #pragma unroll
        for (int L = 0; L < AMPS; ++L)
            amp[L] = unpack(st[jb3 + (L ^ xr)]);
        LOADXX(4); applyXX<4, 0x18>(amp, cc, ss);     // XX(9,10)  on bits(4,3)=(L4,L3)
        LOADXX(5); applyXX<2, 0x06>(amp, cc, ss);     // XX(11,12) on bits(2,1)=(L2,L1)
        LOADRX(10); applyRX<3>(amp, cc, ss);          // bit3
        LOADRX(11); applyRX<2>(amp, cc, ss);
        LOADRX(12); applyRX<1>(amp, cc, ss);
        LOADRX(13); applyRX<0>(amp, cc, ss);          // bit0
        // XX(13,0): flip bit0 (=L0) and bit13 (=lane l0): partner = qperm_l^1(amp[L^1]).
        LOADXX(6);
        #pragma unroll
        for (int L = 0; L < AMPS; L += 2) {
            f2 pv0 = qperm<0xB1>(amp[L + 1]);
            f2 pv1 = qperm<0xB1>(amp[L]);
            amp[L]     = pkfma(cc, amp[L],     pkswz(ss, pv0));
            amp[L + 1] = pkfma(cc, amp[L + 1], pkswz(ss, pv1));
        }
        // RX(0): bit13 = lane l0: partner = qperm_l^1(amp[L])
        LOADRX(0);
        #pragma unroll
        for (int L = 0; L < AMPS; ++L) {
            f2 pv = qperm<0xB1>(amp[L]);
            amp[L] = pkfma(cc, amp[L], pkswz(ss, pv));
        }
        __syncthreads();   // all gate-layout reads complete; E layout may overwrite
        #pragma unroll
        for (int L = 0; L < AMPS; ++L) {
            const unsigned comp = (L & 4) ? ((L & 2) ? tv[L >> 3].w : tv[L >> 3].z)
                                          : ((L & 2) ? tv[L >> 3].y : tv[L >> 3].x);
            const unsigned f = (L & 1) ? (comp >> 16) : (comp & 0xffffu);
            st[f + (f >> 6)] = pack(amp[L]);       // eslot = (f>>6)*65 + (f&63)
        }
    }
    __syncthreads();

    // ==== E: contiguous conflict-free reads; final index f = t*32 + k.
    //   k bits 0..4  -> wires 13..9 (in-register tree U0..U4)
    //   lane bits 0..5 -> wires 8..3 (sign-tracking butterfly d0..d5)
    //   wave bits 0..2 -> wires 2..0 (wave-uniform +-s)
    {
        const h2v* erow = st + t * 32 + (t >> 1);
        float U0 = 0.f, U1 = 0.f, U2 = 0.f;
        float C[4];
        #pragma unroll
        for (int ch = 0; ch < 4; ++ch) {
            float q[8];
            #pragma unroll
            for (int e = 0; e < 8; ++e) {
                const f2 a = unpack(erow[ch * 8 + e]);
                q[e] = fmaf(a.x, a.x, a.y * a.y);
            }
            const float p0 = q[0] + q[1], p1 = q[2] + q[3], p2 = q[4] + q[5], p3 = q[6] + q[7];
            U0 += (q[1] + q[3]) + (q[5] + q[7]);   // k bit0
            U1 += p1 + p3;                          // k bit1
            const float s01 = p0 + p1, s23 = p2 + p3;
            U2 += s23;                              // k bit2
            C[ch] = s01 + s23;
        }
        const float U3 = C[1] + C[3];               // k bit3
        const float U4 = C[2] + C[3];               // k bit4
        const float T  = (C[0] + C[1]) + (C[2] + C[3]);

        // sign-tracking butterfly over 6 lane bits (results valid at lane 0)
        float s = T;
        float d0, d1, d2, d3, d4, d5;
        {
            float o;
            o = __shfl_xor(s, 1);  d0 = s - o; s += o;
            o = __shfl_xor(d0, 2); d0 += o;
            o = __shfl_xor(s, 2);  d1 = s - o; s += o;
            o = __shfl_xor(d0, 4); d0 += o;
            o = __shfl_xor(d1, 4); d1 += o;
            o = __shfl_xor(s, 4);  d2 = s - o; s += o;
            o = __shfl_xor(d0, 8); d0 += o;
            o = __shfl_xor(d1, 8); d1 += o;
            o = __shfl_xor(d2, 8); d2 += o;
            o = __shfl_xor(s, 8);  d3 = s - o; s += o;
            o = __shfl_xor(d0, 16); d0 += o;
            o = __shfl_xor(d1, 16); d1 += o;
            o = __shfl_xor(d2, 16); d2 += o;
            o = __shfl_xor(d3, 16); d3 += o;
            o = __shfl_xor(s, 16);  d4 = s - o; s += o;
            o = __shfl_xor(d0, 32); d0 += o;
            o = __shfl_xor(d1, 32); d1 += o;
            o = __shfl_xor(d2, 32); d2 += o;
            o = __shfl_xor(d3, 32); d3 += o;
            o = __shfl_xor(d4, 32); d4 += o;
            o = __shfl_xor(s, 32);  d5 = s - o; s += o;
        }
        float V0 = U0, V1 = U1, V2 = U2, V3 = U3, V4 = U4;
        #pragma unroll
        for (int m = 1; m < 64; m <<= 1) {
            V0 += __shfl_xor(V0, m);
            V1 += __shfl_xor(V1, m);
            V2 += __shfl_xor(V2, m);
            V3 += __shfl_xor(V3, m);
            V4 += __shfl_xor(V4, m);
        }
        if ((t & 63) == 0) {
            const int wv = t >> 6;           // wave bits = f bits 11,12,13
            float* r = red + wv * NQ;
            r[0]  = (wv & 4) ? -s : s;       // f bit13 -> wire 0
            r[1]  = (wv & 2) ? -s : s;       // f bit12 -> wire 1
            r[2]  = (wv & 1) ? -s : s;       // f bit11 -> wire 2
            r[3]  = d5;                      // f bit10 -> wire 3
            r[4]  = d4;
            r[5]  = d3;
            r[6]  = d2;
            r[7]  = d1;
            r[8]  = d0;                      // f bit5 -> wire 8
            r[9]  = s - 2.f * V4;            // f bit4 -> wire 9
            r[10] = s - 2.f * V3;
            r[11] = s - 2.f * V2;
            r[12] = s - 2.f * V1;
            r[13] = s - 2.f * V0;            // f bit0 -> wire 13
        }
    }
    __syncthreads();
    if (t < NQ) {
        float ssum = 0.f;
        #pragma unroll
        for (int wv = 0; wv < 8; ++wv) ssum += red[wv * NQ + t];
        out[b * NQ + t] = ssum;
    }
    #undef LOADXX
    #undef LOADRX
}

extern "C" void kernel_launch(void* const* d_in, const int* in_sizes, int n_in,
                              void* d_out, int out_size, void* d_ws, size_t ws_size,
                              hipStream_t stream)
{
    (void)n_in; (void)out_size; (void)ws_size;
    const float* cp = (const float*)d_in[0];
    const float* p  = (const float*)d_in[1];
    float* out = (float*)d_out;
    unsigned short* tbl = (unsigned short*)d_ws;        // 32 KiB
    const int B = in_sizes[0] / NQ;   // 512

    perm_tbl_kernel<<<NSTATE / 256, 256, 0, stream>>>(tbl);

    (void)hipFuncSetAttribute(reinterpret_cast<const void*>(qsim_kernel),
                              hipFuncAttributeMaxDynamicSharedMemorySize, SMEM_BYTES);
    qsim_kernel<<<B, NT, SMEM_BYTES, stream>>>(cp, p, tbl, out);
}

// Round 10
// 75.440 us; speedup vs baseline: 1.0626x; 1.0491x over previous
//
#include <hip/hip_runtime.h>

#define NQ 14
#define NSTATE (1 << NQ)
#define NT 256
#define AMPS 64

typedef float  f2  __attribute__((ext_vector_type(2)));
typedef __fp16 h2v __attribute__((ext_vector_type(2)));

// LDS: gate region st[0,16384) h2 (psi-address space, b128-friendly swizzle);
// E region rows stride 68 h2: [0, 256*68=17408) h2 — aliased in time (barriers).
#define N_H2 17408
#define OFF_BTAB  (N_H2*4)                 // 69632
#define OFF_RX3   (OFF_BTAB + 28*8)
#define OFF_XX2   (OFF_RX3 + 28*4)
#define OFF_RED   (OFF_XX2 + 14*4)
#define SMEM_BYTES (OFF_RED + 4*NQ*4)      // ~70.2 KB -> 2 blocks/CU

__device__ __forceinline__ f2 cmul(f2 a, f2 b){
    f2 br = {-b.y, b.x};
    return a.x * b + a.y * br;
}
__device__ __forceinline__ f2 pkswz(f2 ss, f2 y){
    f2 t;
    asm("v_pk_mul_f32 %0, %1, %2 op_sel:[0,1] op_sel_hi:[1,0] neg_hi:[0,1]"
        : "=v"(t) : "v"(ss), "v"(y));
    return t;
}
__device__ __forceinline__ f2 pkfma(f2 a, f2 b, f2 c){
    f2 d;
    asm("v_pk_fma_f32 %0, %1, %2, %3" : "=v"(d) : "v"(a), "v"(b), "v"(c));
    return d;
}
// A' = c*A + s*(B.y,-B.x);  B' = c*B + s*(A.y,-A.x)
__device__ __forceinline__ void rot2(f2& A, f2& B, f2 cc, f2 ss){
    f2 tA = pkswz(ss, B);
    f2 tB = pkswz(ss, A);
    A = pkfma(cc, A, tA);
    B = pkfma(cc, B, tB);
}
__device__ __forceinline__ h2v pack(f2 v){ return __builtin_amdgcn_cvt_pkrtz(v.x, v.y); }
__device__ __forceinline__ f2  unpack(h2v h){ return (f2){(float)h.x, (float)h.y}; }
__device__ __forceinline__ f2  unpack_u(unsigned w){ h2v h = __builtin_bit_cast(h2v, w); return unpack(h); }

template<int CTRL>
__device__ __forceinline__ f2 qperm(f2 v){
    int x = __builtin_amdgcn_mov_dpp(__float_as_int(v.x), CTRL, 0xf, 0xf, true);
    int y = __builtin_amdgcn_mov_dpp(__float_as_int(v.y), CTRL, 0xf, 0xf, true);
    return (f2){__int_as_float(x), __int_as_float(y)};
}
template<int CTRL>
__device__ __forceinline__ float fdpp(float v){
    return __int_as_float(__builtin_amdgcn_mov_dpp(__float_as_int(v), CTRL, 0xf, 0xf, true));
}

template<int P, int M>
__device__ __forceinline__ void applyXX(f2* amp, f2 cc, f2 ss){
    #pragma unroll
    for (int L = 0; L < AMPS; ++L)
        if (!((L >> P) & 1)) rot2(amp[L], amp[L ^ M], cc, ss);
}
template<int R>
__device__ __forceinline__ void applyRX(f2* amp, f2 cc, f2 ss){
    #pragma unroll
    for (int L = 0; L < AMPS; ++L)
        if (!((L >> R) & 1)) rot2(amp[L], amp[L | (1 << R)], cc, ss);
}

// ---- pre-kernel: f = pi^-1(j) (ascending chain; direction verified R6-R9).
// P2 enumeration: j = ((L'>>1)&31) | (t2<<5) | ((L'&1)<<13).
// Store tbl[t2*64 + L'] = f.
__global__ void perm_tbl_kernel(unsigned short* __restrict__ tbl)
{
    const int j = blockIdx.x * blockDim.x + threadIdx.x;   // 0..16383
    int x = j;
    #pragma unroll
    for (int w = 0; w < NQ; ++w) {
        const int p1 = 13 - w;
        const int p2 = 13 - ((w + 1) % NQ);
        const int pt = 13 - ((w + 2) % NQ);
        const int cond = ((x >> p1) & ~(x >> p2)) & 1;
        x ^= cond << pt;
    }
    const int t2 = (j >> 5) & 0xFF;
    const int Lp = ((j >> 13) & 1) | ((j & 31) << 1);
    tbl[t2 * 64 + Lp] = (unsigned short)x;
}

// State bit j -> ownership:
// P1: local L[5:0]=j[12:7]; lanes l0=j6,l1=j5,l2=j4,l3=j3,l4=j2,l5=j1; wave: t6=j0,t7=j13.
// P2: local L'0=j13,L'1=j0,L'2=j1,L'3=j2,L'4=j3,L'5=j4; lanes t2b0=j5..t2b5=j10; wave t2b6=j11,t2b7=j12.
// psi-addr (h2) = t1*64 + (L ^ W1(t1)), W1 = (b0<<2)|(b1<<3)|((b0^b1^b2)<<4), b=t1 bits.
__global__ void __launch_bounds__(NT, 2)
qsim_kernel(const float* __restrict__ cp, const float* __restrict__ p,
            const unsigned short* __restrict__ tblD, float* __restrict__ out)
{
    extern __shared__ __align__(16) char smem[];
    h2v*   st   = reinterpret_cast<h2v*>(smem);
    uint4* stq  = reinterpret_cast<uint4*>(smem);
    f2*    Btab = reinterpret_cast<f2*>(smem + OFF_BTAB);
    float* rx3c = reinterpret_cast<float*>(smem + OFF_RX3);
    float* rx3s = rx3c + 14;
    float* xx2c = reinterpret_cast<float*>(smem + OFF_XX2);
    float* xx2s = xx2c + 7;
    float* red  = reinterpret_cast<float*>(smem + OFF_RED);

    const int b = blockIdx.x;
    const int t = threadIdx.x;
    const float* pb  = p  + b * 42;
    const float* cpb = cp + b * 14;

    // ---- per-block tables (RX1 x XX1 x RZ fused into 7 two-qubit groups) ----
    if (t < 7) {
        const int ws = t, wa = 2*ws, wb = 2*ws + 1;
        float sa, ca; sincosf(0.5f * pb[wa], &sa, &ca);
        float sb, cb; sincosf(0.5f * pb[wb], &sb, &cb);
        f2 s00 = {ca*cb, 0.f};
        f2 s01 = {0.f, -ca*sb};
        f2 s10 = {0.f, -sa*cb};
        f2 s11 = {-sa*sb, 0.f};
        float sx, cx; sincosf(0.5f * cpb[ws], &sx, &cx);
        rot2(s00, s11, (f2){cx,cx}, (f2){sx,sx});
        rot2(s01, s10, (f2){cx,cx}, (f2){sx,sx});
        const float ga = 0.5f * pb[14 + wa], gb = 0.5f * pb[14 + wb];
        float sA, cA; sincosf(ga + gb, &sA, &cA);
        float sB, cB; sincosf(gb - ga, &sB, &cB);
        s00 = cmul(s00, (f2){cA, -sA});
        s11 = cmul(s11, (f2){cA,  sA});
        s01 = cmul(s01, (f2){cB,  sB});
        s10 = cmul(s10, (f2){cB, -sB});
        const int g = 6 - ws;   // group g covers state bits (2g+1, 2g); idx = bit(2g+1)*2 + bit(2g)
        Btab[g*4+0] = s00; Btab[g*4+1] = s01; Btab[g*4+2] = s10; Btab[g*4+3] = s11;
    } else if (t >= 64 && t < 78) {
        const int w = t - 64;
        float s, c; sincosf(0.5f * pb[28 + w], &s, &c);
        rx3c[w] = c; rx3s[w] = s;
    } else if (t >= 128 && t < 135) {
        const int g = t - 128;
        float s, c; sincosf(0.5f * cpb[7 + g], &s, &c);
        xx2c[g] = c; xx2s[g] = s;
    }
    __syncthreads();

    f2 amp[AMPS];
    f2 cc, ss;
    #define LOADXX(g) do { float c_ = xx2c[g], s_ = xx2s[g]; cc = (f2){c_,c_}; ss = (f2){s_,s_}; } while (0)
    #define LOADRX(w) do { float c_ = rx3c[w], s_ = rx3s[w]; cc = (f2){c_,c_}; ss = (f2){s_,s_}; } while (0)

    // ==== P1: build + XX(1,2),(3,4),(5,6) local + XX(7,8) quad + RX(1..8) ====
    {
        // crumb indices from (t, L):  j0=t6 j1=t5 j2=t4 j3=t3 j4=t2 j5=t1 j6=t0 j13=t7
        const int i0 = (((t >> 5) & 1) << 1) | ((t >> 6) & 1);
        const int i1 = (((t >> 3) & 1) << 1) | ((t >> 4) & 1);
        const int i2 = (((t >> 1) & 1) << 1) | ((t >> 2) & 1);
        f2 U = cmul(cmul(Btab[i0], Btab[4 + i1]), Btab[8 + i2]);
        f2 B3v0 = Btab[12 + (t & 1)];                 // L0=0: idx3 = t0
        f2 B3v1 = Btab[12 + 2 + (t & 1)];             // L0=1
        f2 B6v0 = Btab[24 + (((t >> 7) & 1) << 1)];   // L5=0: idx6 = t7*2
        f2 B6v1 = Btab[24 + (((t >> 7) & 1) << 1) + 1];
        f2 UB0 = cmul(U, B3v0), UB1 = cmul(U, B3v1);
        f2 W00 = cmul(UB0, B6v0), W01 = cmul(UB1, B6v0);
        f2 W10 = cmul(UB0, B6v1), W11 = cmul(UB1, B6v1);
        #pragma unroll
        for (int m = 0; m < 16; ++m) {                // m = L[4:1]
            f2 H = cmul(Btab[20 + (m >> 2)], Btab[16 + (m & 3)]);  // B5[idx5]*B4[idx4]
            amp[(m << 1)]          = cmul(W00, H);
            amp[(m << 1) | 1]      = cmul(W01, H);
            amp[32 | (m << 1)]     = cmul(W10, H);
            amp[32 | (m << 1) | 1] = cmul(W11, H);
        }
        LOADXX(0); applyXX<5, 0x30>(amp, cc, ss);     // XX(1,2) bits(12,11)=(L5,L4)
        LOADXX(1); applyXX<3, 0x0C>(amp, cc, ss);     // XX(3,4) bits(10,9)=(L3,L2)
        LOADXX(2); applyXX<1, 0x03>(amp, cc, ss);     // XX(5,6) bits(8,7)=(L1,L0)
        LOADXX(3);                                    // XX(7,8) bits(6,5)=(l0,l1): lane^3
        #pragma unroll
        for (int L = 0; L < AMPS; ++L) { f2 pv = qperm<0x1B>(amp[L]); amp[L] = pkfma(cc, amp[L], pkswz(ss, pv)); }
        LOADRX(1); applyRX<5>(amp, cc, ss);
        LOADRX(2); applyRX<4>(amp, cc, ss);
        LOADRX(3); applyRX<3>(amp, cc, ss);
        LOADRX(4); applyRX<2>(amp, cc, ss);
        LOADRX(5); applyRX<1>(amp, cc, ss);
        LOADRX(6); applyRX<0>(amp, cc, ss);
        LOADRX(7);                                    // bit6 = l0: lane^1
        #pragma unroll
        for (int L = 0; L < AMPS; ++L) { f2 pv = qperm<0xB1>(amp[L]); amp[L] = pkfma(cc, amp[L], pkswz(ss, pv)); }
        LOADRX(8);                                    // bit5 = l1: lane^2
        #pragma unroll
        for (int L = 0; L < AMPS; ++L) { f2 pv = qperm<0x4E>(amp[L]); amp[L] = pkfma(cc, amp[L], pkswz(ss, pv)); }
        // write: 16 x ds_write_b128 at uint4 index t*16 + (m ^ (W1>>2))
        const int w1h = ((t & 1) | ((t >> 1) & 1) << 1 | (((t ^ (t >> 1) ^ (t >> 2)) & 1) << 2));
        #pragma unroll
        for (int m = 0; m < 16; ++m) {
            uint4 pk;
            pk.x = __builtin_bit_cast(unsigned, pack(amp[4*m]));
            pk.y = __builtin_bit_cast(unsigned, pack(amp[4*m + 1]));
            pk.z = __builtin_bit_cast(unsigned, pack(amp[4*m + 2]));
            pk.w = __builtin_bit_cast(unsigned, pack(amp[4*m + 3]));
            stq[t * 16 + (m ^ w1h)] = pk;
        }
    }
    __syncthreads();

    // ==== P2: strided read + XX(9,10),(11,12),(13,0) + RX(9..13,0) all local ====
    {
        uint4 tv[8];
        {
            const uint4* tq = reinterpret_cast<const uint4*>(tblD) + t * 8;
            #pragma unroll
            for (int g = 0; g < 8; ++g) tv[g] = tq[g];   // issue early
        }
        const int sw2 = ((t & 2) >> 1) | ((t & 1) << 1); // t1 low2 = (j6,j5) = (t2b1,t2b0)
        const int Lf  = t >> 2;                           // P1-local L of my amps (thread-const)
        const int w1b = ((sw2 & 1) << 2) | (((sw2 >> 1) & 1) << 3) | ((((sw2 ^ (sw2 >> 1)) & 1)) << 4);
        #pragma unroll
        for (int Lp = 0; Lp < AMPS; ++Lp) {
            const int rev = ((Lp >> 5) & 1) | (((Lp >> 4) & 1) << 1) | (((Lp >> 3) & 1) << 2)
                          | (((Lp >> 2) & 1) << 3) | (((Lp >> 1) & 1) << 4) | ((Lp & 1) << 5);
            const int t1  = sw2 | (rev << 2);
            const int w1v = w1b ^ ((rev & 1) << 4);       // b2 = t1 bit2 = rev bit0
            amp[Lp] = unpack(st[t1 * 64 + (Lf ^ w1v)]);
        }
        LOADXX(4); applyXX<5, 0x30>(amp, cc, ss);     // XX(9,10)  bits(4,3)=(L'5,L'4)
        LOADXX(5); applyXX<3, 0x0C>(amp, cc, ss);     // XX(11,12) bits(2,1)=(L'3,L'2)
        LOADXX(6); applyXX<1, 0x03>(amp, cc, ss);     // XX(13,0)  bits(0,13)=(L'1,L'0)
        LOADRX(9);  applyRX<5>(amp, cc, ss);
        LOADRX(10); applyRX<4>(amp, cc, ss);
        LOADRX(11); applyRX<3>(amp, cc, ss);
        LOADRX(12); applyRX<2>(amp, cc, ss);
        LOADRX(13); applyRX<1>(amp, cc, ss);
        LOADRX(0);  applyRX<0>(amp, cc, ss);
        __syncthreads();   // all gate-layout reads done; E layout may overwrite
        // scatter: eslot = f + 4*(f>>6)  (rows of 64, stride 68)
        #pragma unroll
        for (int Lp = 0; Lp < AMPS; ++Lp) {
            const unsigned word = (Lp & 4) ? ((Lp & 2) ? tv[Lp >> 3].w : tv[Lp >> 3].z)
                                           : ((Lp & 2) ? tv[Lp >> 3].y : tv[Lp >> 3].x);
            const unsigned f = (Lp & 1) ? (word >> 16) : (word & 0xffffu);
            st[f + 4 * (f >> 6)] = pack(amp[Lp]);
        }
    }
    __syncthreads();

    // ==== E: 16 x ds_read_b128; f = t*64 + k ====
    //   k[5:0] -> wires 13..8 (tree U0..U5); lane[5:0] -> wires 7..2 (butterfly);
    //   wave[1:0] -> wires 1,0.
    {
        float T = 0.f, U0 = 0.f, U1 = 0.f, U2 = 0.f, U3 = 0.f, U4 = 0.f, U5 = 0.f;
        #pragma unroll
        for (int m = 0; m < 16; ++m) {
            const uint4 v = stq[t * 17 + m];
            const f2 a0 = unpack_u(v.x), a1 = unpack_u(v.y), a2 = unpack_u(v.z), a3 = unpack_u(v.w);
            const float q0 = fmaf(a0.x, a0.x, a0.y * a0.y);
            const float q1 = fmaf(a1.x, a1.x, a1.y * a1.y);
            const float q2 = fmaf(a2.x, a2.x, a2.y * a2.y);
            const float q3 = fmaf(a3.x, a3.x, a3.y * a3.y);
            const float t23 = q2 + q3;
            const float Tc = (q0 + q1) + t23;
            U0 += q1 + q3;                 // k bit0
            U1 += t23;                     // k bit1
            if (m & 1) U2 += Tc;           // k bit2
            if (m & 2) U3 += Tc;
            if (m & 4) U4 += Tc;
            if (m & 8) U5 += Tc;
            T += Tc;
        }
        // sign-tracking butterfly over 6 lane bits (valid at lane 0); masks 1,2 via DPP
        float s = T;
        float d0, d1, d2, d3, d4, d5;
        {
            float o;
            o = fdpp<0xB1>(s);      d0 = s - o; s += o;
            o = fdpp<0x4E>(d0);     d0 += o;
            o = fdpp<0x4E>(s);      d1 = s - o; s += o;
            o = __shfl_xor(d0, 4);  d0 += o;
            o = __shfl_xor(d1, 4);  d1 += o;
            o = __shfl_xor(s, 4);   d2 = s - o; s += o;
            o = __shfl_xor(d0, 8);  d0 += o;
            o = __shfl_xor(d1, 8);  d1 += o;
            o = __shfl_xor(d2, 8);  d2 += o;
            o = __shfl_xor(s, 8);   d3 = s - o; s += o;
            o = __shfl_xor(d0, 16); d0 += o;
            o = __shfl_xor(d1, 16); d1 += o;
            o = __shfl_xor(d2, 16); d2 += o;
            o = __shfl_xor(d3, 16); d3 += o;
            o = __shfl_xor(s, 16);  d4 = s - o; s += o;
            o = __shfl_xor(d0, 32); d0 += o;
            o = __shfl_xor(d1, 32); d1 += o;
            o = __shfl_xor(d2, 32); d2 += o;
            o = __shfl_xor(d3, 32); d3 += o;
            o = __shfl_xor(d4, 32); d4 += o;
            o = __shfl_xor(s, 32);  d5 = s - o; s += o;
        }
        float V0 = U0, V1 = U1, V2 = U2, V3 = U3, V4 = U4, V5 = U5;
        V0 += fdpp<0xB1>(V0); V1 += fdpp<0xB1>(V1); V2 += fdpp<0xB1>(V2);
        V3 += fdpp<0xB1>(V3); V4 += fdpp<0xB1>(V4); V5 += fdpp<0xB1>(V5);
        V0 += fdpp<0x4E>(V0); V1 += fdpp<0x4E>(V1); V2 += fdpp<0x4E>(V2);
        V3 += fdpp<0x4E>(V3); V4 += fdpp<0x4E>(V4); V5 += fdpp<0x4E>(V5);
        #pragma unroll
        for (int m = 4; m < 64; m <<= 1) {
            V0 += __shfl_xor(V0, m);
            V1 += __shfl_xor(V1, m);
            V2 += __shfl_xor(V2, m);
            V3 += __shfl_xor(V3, m);
            V4 += __shfl_xor(V4, m);
            V5 += __shfl_xor(V5, m);
        }
        if ((t & 63) == 0) {
            const int wv = t >> 6;           // wave bits = f bits 12,13
            float* r = red + wv * NQ;
            r[0]  = (wv & 2) ? -s : s;       // f13 -> wire 0
            r[1]  = (wv & 1) ? -s : s;       // f12 -> wire 1
            r[2]  = d5;                      // f11 -> wire 2
            r[3]  = d4;
            r[4]  = d3;
            r[5]  = d2;
            r[6]  = d1;
            r[7]  = d0;                      // f6 -> wire 7
            r[8]  = s - 2.f * V5;            // f5 -> wire 8
            r[9]  = s - 2.f * V4;
            r[10] = s - 2.f * V3;
            r[11] = s - 2.f * V2;
            r[12] = s - 2.f * V1;
            r[13] = s - 2.f * V0;            // f0 -> wire 13
        }
    }
    __syncthreads();
    if (t < NQ) {
        out[b * NQ + t] = (red[t] + red[NQ + t]) + (red[2 * NQ + t] + red[3 * NQ + t]);
    }
    #undef LOADXX
    #undef LOADRX
}

extern "C" void kernel_launch(void* const* d_in, const int* in_sizes, int n_in,
                              void* d_out, int out_size, void* d_ws, size_t ws_size,
                              hipStream_t stream)
{
    (void)n_in; (void)out_size; (void)ws_size;
    const float* cp = (const float*)d_in[0];
    const float* p  = (const float*)d_in[1];
    float* out = (float*)d_out;
    unsigned short* tbl = (unsigned short*)d_ws;        // 32 KiB
    const int B = in_sizes[0] / NQ;   // 512

    perm_tbl_kernel<<<NSTATE / 256, 256, 0, stream>>>(tbl);

    (void)hipFuncSetAttribute(reinterpret_cast<const void*>(qsim_kernel),
                              hipFuncAttributeMaxDynamicSharedMemorySize, SMEM_BYTES);
    qsim_kernel<<<B, NT, SMEM_BYTES, stream>>>(cp, p, tbl, out);
}